// Round 11
// baseline (73.024 us; speedup 1.0000x reference)
//
#include <hip/hip_runtime.h>
#include <hip/hip_bf16.h>

typedef unsigned char u8;
typedef unsigned short u16;
typedef unsigned int u32;
typedef unsigned long long u64;
typedef __attribute__((ext_vector_type(8))) short short8;
typedef __attribute__((ext_vector_type(4))) short short4v;
typedef __attribute__((ext_vector_type(4))) float f32x4;
typedef __attribute__((ext_vector_type(4))) unsigned int u32x4;
typedef __attribute__((ext_vector_type(2))) unsigned int u32x2;

#define BSZ   4096
#define INF   1024
#define FEAT  512
#define NCLS  1000
#define NPAD  1024
#define DTOT  2048

__device__ __forceinline__ u16 f2bf(float f) {
  unsigned int x = __float_as_uint(f);
  x += 0x7fffu + ((x >> 16) & 1u);   // RNE
  return (u16)(x >> 16);
}
__device__ __forceinline__ float bf2f(u16 h) {
  return __uint_as_float((unsigned int)h << 16);
}
// packed f32x2 -> bf16x2 (RNE), single VALU op
__device__ __forceinline__ u32 cvt_pk(float lo, float hi) {
  u32 r;
  asm("v_cvt_pk_bf16_f32 %0, %1, %2" : "=v"(r) : "v"(lo), "v"(hi));
  return r;
}
// 4x f32 -> 4x fp8 e4m3 packed into one u32 (byte0=a .. byte3=d)
__device__ __forceinline__ u32 pk_fp8x4(float a, float b, float c, float d) {
  u32 r = 0;
  asm("v_cvt_pk_fp8_f32 %0, %1, %2" : "+v"(r) : "v"(a), "v"(b));
  asm("v_cvt_pk_fp8_f32 %0, %1, %2 op_sel:[0,0,1]" : "+v"(r) : "v"(c), "v"(d));
  return r;
}
// fp8 e4m3(fn) -> f32, branch-light bit math (non-hot paths only)
__device__ __forceinline__ float dec_fp8(u8 b) {
  const u32 s = b >> 7, e = (b >> 3) & 15u, m = b & 7u;
  float v = e ? __uint_as_float(((e + 120u) << 23) | (m << 20))
              : (float)m * (1.0f / 512.0f);
  return s ? -v : v;
}
__device__ __forceinline__ void gload_lds16(const void* g, void* l) {
  __builtin_amdgcn_global_load_lds(
      (const __attribute__((address_space(1))) void*)g,
      (__attribute__((address_space(3))) void*)l, 16, 0, 0);
}

// ---- fused prep: W_f/W_r -> bf16 (blocks 0..511); centers -> fp8 + c2 -----
__global__ __launch_bounds__(256) void cvt_prep(const float* __restrict__ W_f,
                                                const float* __restrict__ W_r,
                                                const float* __restrict__ cen,
                                                u16* __restrict__ Wb,
                                                u8* __restrict__ Cb,
                                                float* __restrict__ c2) {
  const int b = blockIdx.x;
  const int t = threadIdx.x;
  if (b < 512) {                       // W convert: 2 x 512x1024 -> bf16
    const int half = b >> 8;
    const int i = (b & 255) * 256 + t;
    const float* in = half ? W_r : W_f;
    const float4* p = (const float4*)in;
    float4 a = p[2 * i], bb = p[2 * i + 1];
    u32x4 o;
    o[0] = cvt_pk(a.x, a.y);  o[1] = cvt_pk(a.z, a.w);
    o[2] = cvt_pk(bb.x, bb.y); o[3] = cvt_pk(bb.z, bb.w);
    *(u32x4*)&Wb[(size_t)half * FEAT * INF + (size_t)i * 8] = o;
    return;
  }
  const int row = b - 512;             // 0..1023 -> centers fp8 + c2
  float s = 0.f;
  if (row < NCLS) {
    const float4* p = (const float4*)(cen + (size_t)row * DTOT) + 2 * t;
    float4 a = p[0], bb = p[1];
    u32x2 o;
    o[0] = pk_fp8x4(a.x, a.y, a.z, a.w);
    o[1] = pk_fp8x4(bb.x, bb.y, bb.z, bb.w);
    *(u32x2*)&Cb[(size_t)row * DTOT + t * 8] = o;
    // c2 from the QUANTIZED center (keeps d2 = ||f^ - c^||^2 consistent)
#pragma unroll
    for (int q = 0; q < 4; ++q) { float f = dec_fp8((u8)(o[0] >> (8 * q))); s += f * f; }
#pragma unroll
    for (int q = 0; q < 4; ++q) { float f = dec_fp8((u8)(o[1] >> (8 * q))); s += f * f; }
  } else {
    u32x2 z = {0, 0};
    *(u32x2*)&Cb[(size_t)row * DTOT + t * 8] = z;
  }
#pragma unroll
  for (int o = 32; o > 0; o >>= 1) s += __shfl_xor(s, o);
  __shared__ float red[4];
  if ((t & 63) == 0) red[t >> 6] = s;
  __syncthreads();
  if (t == 0) c2[row] = red[0] + red[1] + red[2] + red[3];
}

// ---------------- feature GEMM with FUSED x fp32->bf16 convert -------------
// 128x128 tile, 4 waves, both operands dbuf, one barrier/K-step (R10).
// Epilogue now stores Fb as fp8 e4m3 (consumed by dist + combine).
__global__ __launch_bounds__(256) void feat_gemm(const float* __restrict__ x0,
                                                 const float* __restrict__ x1,
                                                 const float* __restrict__ x2,
                                                 const float* __restrict__ x3,
                                                 const u16* __restrict__ Wb,
                                                 const float* __restrict__ bf_,
                                                 const float* __restrict__ br_,
                                                 u8* __restrict__ Fb) {
  __shared__ u16 As[2][128 * 64];
  __shared__ u16 Bs[2][128 * 64];
  const int t = threadIdx.x;
  const int lane = t & 63;
  const int wid = t >> 6;
  const int wr = (wid >> 1) * 64;
  const int wc = (wid & 1) * 64;
  const int lid = blockIdx.x;
  const int swg = (lid & 7) * 64 + (lid >> 3);
  const int bm0 = (swg >> 4) * 128;      // M block
  const int n  = swg & 15;               // N block 0..15
  const int gc0 = n * 128;               // global feat col
  const int g = n >> 2;                  // quadrant 0..3
  const int bn0 = (n & 3) * 128;         // col within W
  const float* A = (g & 2) ? ((g & 1) ? x3 : x2) : ((g & 1) ? x1 : x0);
  const u16* Bt = Wb + (g ? (size_t)FEAT * INF : 0);
  const float* bias = g ? br_ : bf_;

  const int r8 = t >> 3;
  const int kc  = (t & 7) << 3;                   // A: linear global k-chunk
  const int sws = (((t & 7) ^ (r8 & 7)) << 3);    // A: swizzled LDS dest slot
  const int kcs = sws;                            // B: swizzled global source
  const int l15 = lane & 15;
  const int l4 = lane >> 4;
  const int swz = l15 & 7;

  f32x4 acc[4][4] = {};
  float4 ar[8];

  auto ldA = [&](int k0) {
#pragma unroll
    for (int it = 0; it < 4; ++it) {
      const float* p = &A[(size_t)(bm0 + it * 32 + r8) * INF + k0 + kc];
      ar[2 * it]     = *(const float4*)p;
      ar[2 * it + 1] = *(const float4*)(p + 4);
    }
  };
  auto writeA = [&](int buf) {
#pragma unroll
    for (int it = 0; it < 4; ++it) {
      u32x4 o;
      o[0] = cvt_pk(ar[2 * it].x, ar[2 * it].y);
      o[1] = cvt_pk(ar[2 * it].z, ar[2 * it].w);
      o[2] = cvt_pk(ar[2 * it + 1].x, ar[2 * it + 1].y);
      o[3] = cvt_pk(ar[2 * it + 1].z, ar[2 * it + 1].w);
      *(u32x4*)&As[buf][(it * 32 + r8) * 64 + sws] = o;
    }
  };
  auto stageB = [&](int buf, int k0) {
#pragma unroll
    for (int it = 0; it < 4; ++it)
      gload_lds16(&Bt[(size_t)(bn0 + it * 32 + r8) * INF + k0 + kcs],
                  &Bs[buf][(it * 256 + (wid << 6)) * 8]);
  };
  auto comp = [&](int buf) {
#pragma unroll
    for (int ks = 0; ks < 2; ++ks) {
      const int so = (((ks * 4 + l4) ^ swz) << 3);
      short8 av[4], bv[4];
#pragma unroll
      for (int i = 0; i < 4; ++i)
        av[i] = *(const short8*)&As[buf][(wr + i * 16 + l15) * 64 + so];
#pragma unroll
      for (int j = 0; j < 4; ++j)
        bv[j] = *(const short8*)&Bs[buf][(wc + j * 16 + l15) * 64 + so];
#pragma unroll
      for (int i = 0; i < 4; ++i)
#pragma unroll
        for (int j = 0; j < 4; ++j)
          acc[i][j] = __builtin_amdgcn_mfma_f32_16x16x32_bf16(av[i], bv[j],
                                                              acc[i][j], 0, 0, 0);
    }
  };

  const int NT = INF / 64;   // 16
  ldA(0);
  stageB(0, 0);
  writeA(0);
  __syncthreads();
  for (int tt = 0; tt < NT; ++tt) {
    const int cur = tt & 1, nxt = cur ^ 1;
    if (tt + 1 < NT) {
      ldA((tt + 1) * 64);
      stageB(nxt, (tt + 1) * 64);
    }
    comp(cur);
    if (tt + 1 < NT) writeA(nxt);
    __syncthreads();
  }

  // epilogue: bias + relu -> fp8 e4m3 store
#pragma unroll
  for (int j = 0; j < 4; ++j) {
    const int col = gc0 + wc + j * 16 + l15;
    const float bval = bias[bn0 + wc + j * 16 + l15];
#pragma unroll
    for (int i = 0; i < 4; ++i) {
      const int rowb = bm0 + wr + i * 16 + l4 * 4;
      float v0 = fmaxf(acc[i][j][0] + bval, 0.f);
      float v1 = fmaxf(acc[i][j][1] + bval, 0.f);
      float v2 = fmaxf(acc[i][j][2] + bval, 0.f);
      float v3 = fmaxf(acc[i][j][3] + bval, 0.f);
      u32 pk = pk_fp8x4(v0, v1, v2, v3);
#pragma unroll
      for (int r = 0; r < 4; ++r)
        Fb[(size_t)(rowb + r) * DTOT + col] = (u8)(pk >> (8 * r));
    }
  }
}

// ---- distance GEMM split-K (FP8): P[k] = Fb[:, kslice] @ Cb^T -------------
// 128x128 tile, fp8 e4m3 operands: 16 KB staged per K-step (half of bf16),
// mfma_f32_16x16x32_fp8_fp8. 16B-chunk XOR source-swizzle; ds_read_b64
// fragments land at 2-way bank aliasing (free). P stored bf16.
__global__ __launch_bounds__(256) void dist_gemm_sk(const u8* __restrict__ Fb,
                                                    const u8* __restrict__ Cb,
                                                    u16* __restrict__ P) {
  __shared__ u8 As[2][128 * 64];
  __shared__ u8 Bs[2][128 * 64];
  const int t = threadIdx.x;
  const int lane = t & 63;
  const int wid = t >> 6;
  const int wr = (wid >> 1) * 64;
  const int wc = (wid & 1) * 64;
  const int lid = blockIdx.x;
  const int swg = (lid & 7) * 64 + (lid >> 3);
  const int n = swg & 7;
  const int kidx = (swg >> 3) & 1;
  const int bm0 = (swg >> 4) * 128;
  const int bn0 = n * 128;
  const int kbase = kidx * 1024;

  const int r64 = t >> 2;              // staging row 0..63 (+64/round)
  const int c16 = t & 3;               // 16B chunk within 64B k-slice
  const int l15 = lane & 15;
  const int l4 = lane >> 4;

  f32x4 acc[4][4] = {};

  auto stage = [&](int buf, int k0) {
#pragma unroll
    for (int it = 0; it < 2; ++it) {
      const int row = it * 64 + r64;
      const int sc = (c16 ^ (row & 3)) << 4;   // pre-swizzled global chunk
      gload_lds16(&Fb[(size_t)(bm0 + row) * DTOT + k0 + sc],
                  &As[buf][row * 64 + c16 * 16]);
      gload_lds16(&Cb[(size_t)(bn0 + row) * DTOT + k0 + sc],
                  &Bs[buf][row * 64 + c16 * 16]);
    }
  };
  auto comp = [&](int buf) {
#pragma unroll
    for (int ks = 0; ks < 2; ++ks) {
      const int g16 = ks * 2 + (l4 >> 1);      // global 16B chunk of fragment
      const int h8 = (l4 & 1) << 3;            // 8B half within chunk
      long av[4], bv[4];
#pragma unroll
      for (int i = 0; i < 4; ++i) {
        const int row = wr + i * 16 + l15;
        av[i] = *(const long*)&As[buf][row * 64 + ((g16 ^ (row & 3)) << 4) + h8];
      }
#pragma unroll
      for (int j = 0; j < 4; ++j) {
        const int row = wc + j * 16 + l15;
        bv[j] = *(const long*)&Bs[buf][row * 64 + ((g16 ^ (row & 3)) << 4) + h8];
      }
#pragma unroll
      for (int i = 0; i < 4; ++i)
#pragma unroll
        for (int j = 0; j < 4; ++j)
          acc[i][j] = __builtin_amdgcn_mfma_f32_16x16x32_fp8_fp8(av[i], bv[j],
                                                                 acc[i][j], 0, 0, 0);
    }
  };

  stage(0, kbase);
  __syncthreads();
  for (int k0 = kbase; k0 < kbase + 1024; k0 += 128) {
    stage(1, k0 + 64);
    comp(0);
    __syncthreads();
    if (k0 + 128 < kbase + 1024) stage(0, k0 + 128);
    comp(1);
    __syncthreads();
  }

  u16* Pk = P + (size_t)kidx * BSZ * NPAD;
#pragma unroll
  for (int j = 0; j < 4; ++j) {
    const int col = bn0 + wc + j * 16 + l15;
#pragma unroll
    for (int i = 0; i < 4; ++i) {
#pragma unroll
      for (int r = 0; r < 4; ++r) {
        const int row = bm0 + wr + i * 16 + l4 * 4 + r;
        Pk[(size_t)row * NPAD + col] = f2bf(acc[i][j][r]);
      }
    }
  }
}

// ------ combine (fused f2): f2 = ||Fb_fp8[row]||^2 in-block, then
//        out = -0.1*sqrt(max(f2 + c2 - 2*(P0+P1), 0)). One block per row.
__global__ __launch_bounds__(256) void combine(const u8* __restrict__ Fb,
                                               const u16* __restrict__ P,
                                               const float* __restrict__ c2,
                                               float* __restrict__ out) {
  const int row = blockIdx.x;
  const int t = threadIdx.x;
  u64 v = *(const u64*)&Fb[(size_t)row * DTOT + t * 8];
  float s = 0.f;
#pragma unroll
  for (int q = 0; q < 8; ++q) { float f = dec_fp8((u8)(v >> (8 * q))); s += f * f; }
#pragma unroll
  for (int o = 32; o > 0; o >>= 1) s += __shfl_xor(s, o);
  __shared__ float red[4];
  if ((t & 63) == 0) red[t >> 6] = s;
  __syncthreads();
  const float fv = red[0] + red[1] + red[2] + red[3];

  const int c = t * 4;
  if (c >= NCLS) return;
  const short4v p0 = *(const short4v*)&P[(size_t)row * NPAD + c];
  const short4v p1 = *(const short4v*)&P[(size_t)(BSZ + row) * NPAD + c];
  const float4 cv = *(const float4*)&c2[c];
  float4 o;
  o.x = -0.1f * sqrtf(fmaxf(fv + cv.x - 2.f * (bf2f((u16)p0[0]) + bf2f((u16)p1[0])), 0.f));
  o.y = -0.1f * sqrtf(fmaxf(fv + cv.y - 2.f * (bf2f((u16)p0[1]) + bf2f((u16)p1[1])), 0.f));
  o.z = -0.1f * sqrtf(fmaxf(fv + cv.z - 2.f * (bf2f((u16)p0[2]) + bf2f((u16)p1[2])), 0.f));
  o.w = -0.1f * sqrtf(fmaxf(fv + cv.w - 2.f * (bf2f((u16)p0[3]) + bf2f((u16)p1[3])), 0.f));
  *(float4*)&out[(size_t)row * NCLS + c] = o;
}

extern "C" void kernel_launch(void* const* d_in, const int* in_sizes, int n_in,
                              void* d_out, int out_size, void* d_ws, size_t ws_size,
                              hipStream_t stream) {
  const float* x    = (const float*)d_in[0];
  const float* x90  = (const float*)d_in[1];
  const float* x180 = (const float*)d_in[2];
  const float* x270 = (const float*)d_in[3];
  const float* W_f  = (const float*)d_in[4];
  const float* b_f  = (const float*)d_in[5];
  const float* W_r  = (const float*)d_in[6];
  const float* b_r  = (const float*)d_in[7];
  const float* cen  = (const float*)d_in[8];
  float* out = (float*)d_out;

  u16* Wb = (u16*)d_ws;                         // [2][512][1024] bf16
  u8*  Cb = (u8*)(Wb + 2ull * FEAT * INF);      // [1024][2048] fp8
  u8*  Fb = Cb + (size_t)NPAD * DTOT;           // [4096][2048] fp8
  u16* P  = (u16*)(Fb + (size_t)BSZ * DTOT);    // [2][4096][1024] bf16
  float* c2 = (float*)(P + 2ull * BSZ * NPAD);  // [1024]

  cvt_prep<<<1536, 256, 0, stream>>>(W_f, W_r, cen, Wb, Cb, c2);
  feat_gemm<<<512, 256, 0, stream>>>(x, x90, x180, x270, Wb, b_f, b_r, Fb);
  dist_gemm_sk<<<512, 256, 0, stream>>>(Fb, Cb, P);
  combine<<<BSZ, 256, 0, stream>>>(Fb, P, c2, out);
}